// Round 7
// baseline (2231.456 us; speedup 1.0000x reference)
//
#include <hip/hip_runtime.h>
#include <math.h>

#define DIM 32
#define BLK 256
#define JSPLIT 16   // j-chunks -> grid.y ; 16 fp64-atomic writers per out row
#define RI   2      // i-tiles per wave (32 rows) -> 512 pairs per wave-jtile
#define ITPB (4*RI) // i-tiles per block (8 tiles = 128 rows)
#define GTT  16     // j-tiles between fp32->fp64 flushes (256 j)

typedef _Float16 half8 __attribute__((ext_vector_type(8)));
typedef float    f32x4 __attribute__((ext_vector_type(4)));
typedef float    f32x2 __attribute__((ext_vector_type(2)));

struct hl16 { half8 h; half8 l; };   // 32 B fragment record (hi + lo plane)

// out[i] = 2^(c2*||x_i||^2) * sum_j 2^(bf_j + <mf*x_i, y_j>)
//   c2 = -ls*log2(e) (fp64, exact per-i factor in epilogue)
//   f16 hi/lo split (lo plane *2^12 to stay f16-normal):
//     cm = Ah*Bh ; cl = Ah*Bl + Al*Bh ; f = cm + (cl*2^-12 + bf_j)
//   exp2 fp32; fp32 partials flushed to fp64 every GTT tiles; fp64 atomics.
// R6: SOFTWARE PIPELINE — step s: load B(s+2), MFMA B(s+1), epilogue on
//   tile s's results (cmP/clP). MFMA result latency off the critical path;
//   matrix / trans / VALU pipes overlap within each wave. RI=2 keeps
//   ~100 VGPRs -> 4 waves/SIMD.

__global__ __launch_bounds__(BLK) void rbf_prep(
    const float* __restrict__ lsp, const float* __restrict__ x,
    const float* __restrict__ y, int n, int m,
    double* __restrict__ acc, double* __restrict__ scale,
    float* __restrict__ bf, hl16* __restrict__ xhl, hl16* __restrict__ yhl)
{
    int i = blockIdx.x * BLK + threadIdx.x;
    const double c2 = -(double)lsp[0] * 1.4426950408889634074; // -ls*log2(e)
    const float mf = (float)(-2.0 * c2);
    if (i < n) {
        const float* xp = x + (size_t)i * DIM;
        double xs = 0.0;
        #pragma unroll
        for (int d = 0; d < DIM; ++d) { double v = (double)xp[d]; xs = fma(v, v, xs); }
        acc[i] = 0.0;
        scale[i] = exp2(c2 * xs);
        const int it = i >> 4, r15 = i & 15;
        #pragma unroll
        for (int q = 0; q < 4; ++q) {
            half8 hh, hl;
            #pragma unroll
            for (int d = 0; d < 8; ++d) {
                float v = xp[q * 8 + d] * mf;
                _Float16 h = (_Float16)v;
                hh[d] = h;
                hl[d] = (_Float16)((v - (float)h) * 4096.0f);
            }
            xhl[it * 64 + q * 16 + r15].h = hh;
            xhl[it * 64 + q * 16 + r15].l = hl;
        }
    }
    if (i < m) {
        const float* yp = y + (size_t)i * DIM;
        double ys = 0.0;
        #pragma unroll
        for (int d = 0; d < DIM; ++d) { double v = (double)yp[d]; ys = fma(v, v, ys); }
        bf[i] = (float)(c2 * ys);
        const int it = i >> 4, r15 = i & 15;
        #pragma unroll
        for (int q = 0; q < 4; ++q) {
            half8 hh, hl;
            #pragma unroll
            for (int d = 0; d < 8; ++d) {
                float v = yp[q * 8 + d];
                _Float16 h = (_Float16)v;
                hh[d] = h;
                hl[d] = (_Float16)((v - (float)h) * 4096.0f);
            }
            yhl[it * 64 + q * 16 + r15].h = hh;
            yhl[it * 64 + q * 16 + r15].l = hl;
        }
    }
}

__global__ __launch_bounds__(BLK, 4) void rbf_main(
    const hl16* __restrict__ xhl, const hl16* __restrict__ yhl,
    const float* __restrict__ bf, double* __restrict__ acc, int chunk_j)
{
    const int lane = threadIdx.x & 63;
    const int wave = threadIdx.x >> 6;
    const int itbase = blockIdx.x * ITPB + wave * RI;
    const int c15 = lane & 15;

    half8 ah[RI], al[RI];
    #pragma unroll
    for (int r = 0; r < RI; ++r) {
        ah[r] = xhl[(itbase + r) * 64 + lane].h;
        al[r] = xhl[(itbase + r) * 64 + lane].l;
    }

    const int jt0 = (blockIdx.y * chunk_j) >> 4;
    const int njt = chunk_j >> 4;                 // 128 j-tiles per chunk

    const f32x4 zq = {0.0f, 0.0f, 0.0f, 0.0f};    // persistent zero C quad
    const float k12 = 0x1p-12f;

    double accd[RI][4];
    #pragma unroll
    for (int r = 0; r < RI; ++r)
        #pragma unroll
        for (int e = 0; e < 4; ++e) accd[r][e] = 0.0;

    // ---- pipeline prologue ----
    // tile t lives in B-slot (t & 1)
    half8 bh[2], bl[2];
    float bfq[2];
    {
        const hl16* yt0 = yhl + (size_t)jt0 * 64;
        bh[0] = yt0[lane].h; bl[0] = yt0[lane].l;
        bfq[0] = bf[jt0 * 16 + c15];
    }
    f32x4 cmP[RI], clP[RI];
    #pragma unroll
    for (int r = 0; r < RI; ++r) {
        cmP[r] = __builtin_amdgcn_mfma_f32_16x16x32_f16(ah[r], bh[0], zq, 0, 0, 0);
        f32x4 c = __builtin_amdgcn_mfma_f32_16x16x32_f16(ah[r], bl[0], zq, 0, 0, 0);
        clP[r] = __builtin_amdgcn_mfma_f32_16x16x32_f16(al[r], bh[0], c, 0, 0, 0);
    }
    float bfP = bfq[0];
    {
        const hl16* yt1 = yhl + (size_t)(jt0 + 1) * 64;
        bh[1] = yt1[lane].h; bl[1] = yt1[lane].l;
        bfq[1] = bf[(jt0 + 1) * 16 + c15];
    }

    for (int g = 0; g < njt / GTT; ++g) {
        f32x2 accf[RI][2];
        #pragma unroll
        for (int r = 0; r < RI; ++r) {
            accf[r][0] = (f32x2){0.0f, 0.0f};
            accf[r][1] = (f32x2){0.0f, 0.0f};
        }

        #pragma unroll
        for (int tt = 0; tt < GTT; ++tt) {
            const int s  = g * GTT + tt;          // epilogue tile (pipeline tail)
            int sl = s + 2; if (sl >= njt) sl -= njt;   // tile to load
            int sm = s + 1; if (sm >= njt) sm -= njt;   // tile to MFMA

            // (1) issue loads for tile s+2 into slot (s&1)
            const hl16* ytl = yhl + (size_t)(jt0 + sl) * 64;
            bh[sl & 1] = ytl[lane].h;
            bl[sl & 1] = ytl[lane].l;
            bfq[sl & 1] = (bf + (jt0 + sl) * 16)[c15];

            // (2) issue MFMAs for tile s+1 from slot ((s+1)&1)
            f32x4 cmC[RI], clC[RI];
            const int mslot = sm & 1;
            #pragma unroll
            for (int r = 0; r < RI; ++r) {
                cmC[r] = __builtin_amdgcn_mfma_f32_16x16x32_f16(ah[r], bh[mslot], zq, 0, 0, 0);
                f32x4 c = __builtin_amdgcn_mfma_f32_16x16x32_f16(ah[r], bl[mslot], zq, 0, 0, 0);
                clC[r] = __builtin_amdgcn_mfma_f32_16x16x32_f16(al[r], bh[mslot], c, 0, 0, 0);
            }
            float bfC = bfq[mslot];

            // (3) epilogue on tile s (results computed last step — latency hidden)
            const f32x2 bf2 = {bfP, bfP};
            #pragma unroll
            for (int r = 0; r < RI; ++r) {
                f32x2 f0 = {cmP[r][0], cmP[r][1]}, f1 = {cmP[r][2], cmP[r][3]};
                f32x2 l0 = {clP[r][0], clP[r][1]}, l1 = {clP[r][2], clP[r][3]};
                l0 = l0 * k12 + bf2;               // v_pk_fma_f32
                l1 = l1 * k12 + bf2;
                f0 = f0 + l0;                      // v_pk_add_f32
                f1 = f1 + l1;
                f32x2 e0 = {__builtin_amdgcn_exp2f(f0.x), __builtin_amdgcn_exp2f(f0.y)};
                f32x2 e1 = {__builtin_amdgcn_exp2f(f1.x), __builtin_amdgcn_exp2f(f1.y)};
                accf[r][0] += e0;
                accf[r][1] += e1;
            }

            // (4) rotate pipeline regs (SSA-renamed inside the unroll)
            #pragma unroll
            for (int r = 0; r < RI; ++r) { cmP[r] = cmC[r]; clP[r] = clC[r]; }
            bfP = bfC;
        }
        #pragma unroll
        for (int r = 0; r < RI; ++r) {
            accd[r][0] += (double)accf[r][0].x;
            accd[r][1] += (double)accf[r][0].y;
            accd[r][2] += (double)accf[r][1].x;
            accd[r][3] += (double)accf[r][1].y;
        }
    }

    // sum the 16 j-columns: fp64 butterfly across the 16-lane col groups
    #pragma unroll
    for (int r = 0; r < RI; ++r) {
        #pragma unroll
        for (int e = 0; e < 4; ++e) {
            double v = accd[r][e];
            v += __shfl_xor(v, 1, 64);
            v += __shfl_xor(v, 2, 64);
            v += __shfl_xor(v, 4, 64);
            v += __shfl_xor(v, 8, 64);
            if (c15 == 0) {
                int row = (itbase + r) * 16 + (lane >> 4) * 4 + e;
                atomicAdd(&acc[row], v);   // fp64, JSPLIT writers per row
            }
        }
    }
}

__global__ __launch_bounds__(BLK) void rbf_finish(
    const double* __restrict__ acc, const double* __restrict__ scale,
    float* __restrict__ out, int n)
{
    int i = blockIdx.x * BLK + threadIdx.x;
    if (i < n) out[i] = (float)(acc[i] * scale[i]);
}

extern "C" void kernel_launch(void* const* d_in, const int* in_sizes, int n_in,
                              void* d_out, int out_size, void* d_ws, size_t ws_size,
                              hipStream_t stream)
{
    const float* ls = (const float*)d_in[0];
    const float* x  = (const float*)d_in[1];
    const float* y  = (const float*)d_in[2];
    const int n = in_sizes[1] / DIM;   // 32768
    const int m = in_sizes[2] / DIM;   // 32768
    float* out = (float*)d_out;

    // ws: acc[n] f64 | scale[n] f64 | bf[m] f32 | xhl (n/16*64 hl16) | yhl
    // total ~8.6 MB
    char* ws = (char*)d_ws;
    double* acc   = (double*)ws;
    double* scale = acc + n;
    float*  bf    = (float*)(scale + n);
    hl16*   xhl   = (hl16*)(bf + m);
    hl16*   yhl   = xhl + (size_t)(n / 16) * 64;

    const int nm = (n > m) ? n : m;
    rbf_prep<<<(nm + BLK - 1) / BLK, BLK, 0, stream>>>(
        ls, x, y, n, m, acc, scale, bf, xhl, yhl);

    const int chunk = m / JSPLIT;                 // 2048
    dim3 grid(n / (16 * ITPB), JSPLIT);           // 256 x 16
    rbf_main<<<grid, BLK, 0, stream>>>(xhl, yhl, bf, acc, chunk);

    rbf_finish<<<(n + BLK - 1) / BLK, BLK, 0, stream>>>(acc, scale, out, n);
}

// Round 8
// 480.566 us; speedup vs baseline: 4.6434x; 4.6434x over previous
//
#include <hip/hip_runtime.h>
#include <math.h>

#define DIM 32
#define BLK 256
#define JSPLIT 16   // j-chunks -> grid.y ; 16 fp64-atomic writers per out row
#define RI   2      // i-tiles per wave (32 rows) -> 512 pairs per wave-jtile
#define ITPB (4*RI) // i-tiles per block (8 tiles = 128 rows)
#define GTT  16     // j-tiles between fp32->fp64 flushes (256 j)

typedef _Float16 half8 __attribute__((ext_vector_type(8)));
typedef float    f32x4 __attribute__((ext_vector_type(4)));
typedef float    f32x2 __attribute__((ext_vector_type(2)));

struct hl16 { half8 h; half8 l; };   // 32 B fragment record (hi + lo plane)

// out[i] = 2^(c2*||x_i||^2) * sum_j 2^(bf_j + <mf*x_i, y_j>)
//   c2 = -ls*log2(e) (fp64, exact per-i factor in epilogue)
//   f16 hi/lo split (lo plane *2^12 to stay f16-normal):
//     cm = Ah*Bh ; cl = Ah*Bl + Al*Bh ; f = cm + (cl*2^-12 + bf_j)
//   2^f computed WITHOUT v_exp_f32 (trans pipe was the R3-R5 wall):
//     fc = max(f,-126); t = fc + 1.5*2^23 (RNE to int, exact); n = t - K;
//     r = fc - n (exact, in [-1/2,1/2]); 2^r = deg-7 Taylor Horner (pk_fma);
//     2^n bits = ((t_bits<<23) + 0x3F800000)  [valid for n in [-126,127]]
//   fp32 partials flushed to fp64 every GTT tiles; fp64 atomics.
// R7: R4 structure (static parity double-buffer — R6's runtime slot indices
//   caused a v_cndmask/scratch storm, never again) + polynomial exp2.

__global__ __launch_bounds__(BLK) void rbf_prep(
    const float* __restrict__ lsp, const float* __restrict__ x,
    const float* __restrict__ y, int n, int m,
    double* __restrict__ acc, double* __restrict__ scale,
    float* __restrict__ bf, hl16* __restrict__ xhl, hl16* __restrict__ yhl)
{
    int i = blockIdx.x * BLK + threadIdx.x;
    const double c2 = -(double)lsp[0] * 1.4426950408889634074; // -ls*log2(e)
    const float mf = (float)(-2.0 * c2);
    if (i < n) {
        const float* xp = x + (size_t)i * DIM;
        double xs = 0.0;
        #pragma unroll
        for (int d = 0; d < DIM; ++d) { double v = (double)xp[d]; xs = fma(v, v, xs); }
        acc[i] = 0.0;
        scale[i] = exp2(c2 * xs);
        const int it = i >> 4, r15 = i & 15;
        #pragma unroll
        for (int q = 0; q < 4; ++q) {
            half8 hh, hl;
            #pragma unroll
            for (int d = 0; d < 8; ++d) {
                float v = xp[q * 8 + d] * mf;
                _Float16 h = (_Float16)v;
                hh[d] = h;
                hl[d] = (_Float16)((v - (float)h) * 4096.0f);
            }
            xhl[it * 64 + q * 16 + r15].h = hh;
            xhl[it * 64 + q * 16 + r15].l = hl;
        }
    }
    if (i < m) {
        const float* yp = y + (size_t)i * DIM;
        double ys = 0.0;
        #pragma unroll
        for (int d = 0; d < DIM; ++d) { double v = (double)yp[d]; ys = fma(v, v, ys); }
        bf[i] = (float)(c2 * ys);
        const int it = i >> 4, r15 = i & 15;
        #pragma unroll
        for (int q = 0; q < 4; ++q) {
            half8 hh, hl;
            #pragma unroll
            for (int d = 0; d < 8; ++d) {
                float v = yp[q * 8 + d];
                _Float16 h = (_Float16)v;
                hh[d] = h;
                hl[d] = (_Float16)((v - (float)h) * 4096.0f);
            }
            yhl[it * 64 + q * 16 + r15].h = hh;
            yhl[it * 64 + q * 16 + r15].l = hl;
        }
    }
}

// deg-7 Taylor for 2^r on [-0.5, 0.5]; max rel err ~5.2e-9, bias ~6e-10
#define C7 1.5252733804059838e-05f
#define C6 0.00015403530393381608f
#define C5 0.0013333558146428443f
#define C4 0.009618129107628477f
#define C3 0.05550410866482158f
#define C2f 0.2402265069591007f
#define C1f 0.6931471805599453f
#define KMAGIC 12582912.0f   // 1.5 * 2^23

__device__ __forceinline__ void exp2_acc2(f32x2 f, f32x2& accv) {
    // clamp (deep-tail pairs: exp2 would be 0; we return 2^-126 ~ 1e-38)
    f32x2 fc = { fmaxf(f.x, -126.0f), fmaxf(f.y, -126.0f) };
    f32x2 t  = fc + (f32x2){KMAGIC, KMAGIC};    // RNE to integer, exact
    f32x2 nf = t - (f32x2){KMAGIC, KMAGIC};     // n as float, exact
    f32x2 r  = fc - nf;                         // exact, in [-1/2, 1/2]
    f32x2 p  = {C7, C7};
    p = p * r + (f32x2){C6, C6};
    p = p * r + (f32x2){C5, C5};
    p = p * r + (f32x2){C4, C4};
    p = p * r + (f32x2){C3, C3};
    p = p * r + (f32x2){C2f, C2f};
    p = p * r + (f32x2){C1f, C1f};
    p = p * r + (f32x2){1.0f, 1.0f};
    // 2^n from t's bits: mantissa(t) = 0x400000 + n; (bits<<23)+0x3F800000
    unsigned sx = (__float_as_uint(t.x) << 23) + 0x3F800000u;
    unsigned sy = (__float_as_uint(t.y) << 23) + 0x3F800000u;
    f32x2 s = { __uint_as_float(sx), __uint_as_float(sy) };
    accv = p * s + accv;                        // v_pk_fma_f32
}

__global__ __launch_bounds__(BLK, 4) void rbf_main(
    const hl16* __restrict__ xhl, const hl16* __restrict__ yhl,
    const float* __restrict__ bf, double* __restrict__ acc, int chunk_j)
{
    const int lane = threadIdx.x & 63;
    const int wave = threadIdx.x >> 6;
    const int itbase = blockIdx.x * ITPB + wave * RI;
    const int c15 = lane & 15;

    half8 ah[RI], al[RI];
    #pragma unroll
    for (int r = 0; r < RI; ++r) {
        ah[r] = xhl[(itbase + r) * 64 + lane].h;
        al[r] = xhl[(itbase + r) * 64 + lane].l;
    }

    const int jt0 = (blockIdx.y * chunk_j) >> 4;
    const int njt = chunk_j >> 4;                 // 128 j-tiles per chunk

    const f32x4 zq = {0.0f, 0.0f, 0.0f, 0.0f};    // persistent zero C quad
    const float k12 = 0x1p-12f;

    double accd[RI][4];
    #pragma unroll
    for (int r = 0; r < RI; ++r)
        #pragma unroll
        for (int e = 0; e < 4; ++e) accd[r][e] = 0.0;

    // parity double-buffered B fragments (tt&1 is compile-time in the unroll)
    half8 bh[2], bl[2];
    float bfv[2];
    bh[0] = yhl[(size_t)jt0 * 64 + lane].h;
    bl[0] = yhl[(size_t)jt0 * 64 + lane].l;
    bfv[0] = bf[jt0 * 16 + c15];

    for (int g = 0; g < njt / GTT; ++g) {
        f32x2 accf[RI][2];
        #pragma unroll
        for (int r = 0; r < RI; ++r) {
            accf[r][0] = (f32x2){0.0f, 0.0f};
            accf[r][1] = (f32x2){0.0f, 0.0f};
        }

        #pragma unroll
        for (int tt = 0; tt < GTT; ++tt) {
            const int cur = tt & 1, nxt = cur ^ 1;
            const int jt = jt0 + g * GTT + tt;
            int jn = jt + 1; if (jn >= jt0 + njt) jn = jt0;   // scalar cselect
            const hl16* __restrict__ yt = yhl + (size_t)jn * 64;
            bh[nxt] = yt[lane].h;
            bl[nxt] = yt[lane].l;
            bfv[nxt] = (bf + jn * 16)[c15];

            f32x2 bf2 = {bfv[cur], bfv[cur]};
            #pragma unroll
            for (int r = 0; r < RI; ++r) {
                f32x4 cm = __builtin_amdgcn_mfma_f32_16x16x32_f16(ah[r], bh[cur], zq, 0, 0, 0);
                f32x4 cl = __builtin_amdgcn_mfma_f32_16x16x32_f16(ah[r], bl[cur], zq, 0, 0, 0);
                cl = __builtin_amdgcn_mfma_f32_16x16x32_f16(al[r], bh[cur], cl, 0, 0, 0);
                f32x2 f0 = {cm[0], cm[1]}, f1 = {cm[2], cm[3]};
                f32x2 l0 = {cl[0], cl[1]}, l1 = {cl[2], cl[3]};
                l0 = l0 * k12 + bf2;               // v_pk_fma_f32
                l1 = l1 * k12 + bf2;
                f0 = f0 + l0;                      // v_pk_add_f32
                f1 = f1 + l1;
                exp2_acc2(f0, accf[r][0]);         // poly 2^f, no v_exp_f32
                exp2_acc2(f1, accf[r][1]);
            }
        }
        #pragma unroll
        for (int r = 0; r < RI; ++r) {
            accd[r][0] += (double)accf[r][0].x;
            accd[r][1] += (double)accf[r][0].y;
            accd[r][2] += (double)accf[r][1].x;
            accd[r][3] += (double)accf[r][1].y;
        }
    }

    // sum the 16 j-columns: fp64 butterfly across the 16-lane col groups
    #pragma unroll
    for (int r = 0; r < RI; ++r) {
        #pragma unroll
        for (int e = 0; e < 4; ++e) {
            double v = accd[r][e];
            v += __shfl_xor(v, 1, 64);
            v += __shfl_xor(v, 2, 64);
            v += __shfl_xor(v, 4, 64);
            v += __shfl_xor(v, 8, 64);
            if (c15 == 0) {
                int row = (itbase + r) * 16 + (lane >> 4) * 4 + e;
                atomicAdd(&acc[row], v);   // fp64, JSPLIT writers per row
            }
        }
    }
}

__global__ __launch_bounds__(BLK) void rbf_finish(
    const double* __restrict__ acc, const double* __restrict__ scale,
    float* __restrict__ out, int n)
{
    int i = blockIdx.x * BLK + threadIdx.x;
    if (i < n) out[i] = (float)(acc[i] * scale[i]);
}

extern "C" void kernel_launch(void* const* d_in, const int* in_sizes, int n_in,
                              void* d_out, int out_size, void* d_ws, size_t ws_size,
                              hipStream_t stream)
{
    const float* ls = (const float*)d_in[0];
    const float* x  = (const float*)d_in[1];
    const float* y  = (const float*)d_in[2];
    const int n = in_sizes[1] / DIM;   // 32768
    const int m = in_sizes[2] / DIM;   // 32768
    float* out = (float*)d_out;

    // ws: acc[n] f64 | scale[n] f64 | bf[m] f32 | xhl (n/16*64 hl16) | yhl
    // total ~8.6 MB
    char* ws = (char*)d_ws;
    double* acc   = (double*)ws;
    double* scale = acc + n;
    float*  bf    = (float*)(scale + n);
    hl16*   xhl   = (hl16*)(bf + m);
    hl16*   yhl   = xhl + (size_t)(n / 16) * 64;

    const int nm = (n > m) ? n : m;
    rbf_prep<<<(nm + BLK - 1) / BLK, BLK, 0, stream>>>(
        ls, x, y, n, m, acc, scale, bf, xhl, yhl);

    const int chunk = m / JSPLIT;                 // 2048
    dim3 grid(n / (16 * ITPB), JSPLIT);           // 256 x 16
    rbf_main<<<grid, BLK, 0, stream>>>(xhl, yhl, bf, acc, chunk);

    rbf_finish<<<(n + BLK - 1) / BLK, BLK, 0, stream>>>(acc, scale, out, n);
}

// Round 9
// 304.334 us; speedup vs baseline: 7.3323x; 1.5791x over previous
//
#include <hip/hip_runtime.h>
#include <math.h>

#define DIM 32
#define BLK 256
#define JSPLIT 16   // j-chunks -> grid.y ; 16 fp64-atomic writers per out row
#define RI   2      // i-tiles per wave (32 rows) -> 512 pairs per wave-jtile
#define ITPB (4*RI) // i-tiles per block (8 tiles = 128 rows)
#define GTT  16     // j-tiles between fp32->fp64 flushes (256 j)

typedef _Float16 half8 __attribute__((ext_vector_type(8)));
typedef float    f32x4 __attribute__((ext_vector_type(4)));

struct hl16 { half8 h; half8 l; };   // 32 B fragment record (hi + lo plane)

// out[i] = 2^(c2*||x_i||^2) * sum_j 2^(bf_j + <mf*x_i, y_j>)
//   c2 = -ls*log2(e) (fp64, exact per-i factor in epilogue)
//   f16 hi/lo split (lo plane *2^12 to stay f16-normal):
//     cm = Ah*Bh ; cl = Ah*Bl + (Al*Bh + bf*2^12) ; f = fma(cl, 2^-12, cm)
//   exp2 = v_exp_f32 (R7 poly regressed); fp32 partials -> fp64 every GTT
//   tiles; fp64 atomics.
// R8 instruction diet (R4 was ~90 VALU insts/tile vs ~35 in source):
//   - per-group uniform base + static tile offsets (addressing on scalar pipe)
//   - no wrap cselects: one-past-end prefetch never consumed; ws layout
//     ordered bf -> yhl -> xhl so stray prefetch loads stay inside d_ws
//   - bf folded into cl's MFMA C-operand (splat shared across r)
//   - scalar epilogue straight off MFMA quads (no vector-glue movs)

__global__ __launch_bounds__(BLK) void rbf_prep(
    const float* __restrict__ lsp, const float* __restrict__ x,
    const float* __restrict__ y, int n, int m,
    double* __restrict__ acc, double* __restrict__ scale,
    float* __restrict__ bf, hl16* __restrict__ xhl, hl16* __restrict__ yhl)
{
    int i = blockIdx.x * BLK + threadIdx.x;
    const double c2 = -(double)lsp[0] * 1.4426950408889634074; // -ls*log2(e)
    const float mf = (float)(-2.0 * c2);
    if (i < n) {
        const float* xp = x + (size_t)i * DIM;
        double xs = 0.0;
        #pragma unroll
        for (int d = 0; d < DIM; ++d) { double v = (double)xp[d]; xs = fma(v, v, xs); }
        acc[i] = 0.0;
        scale[i] = exp2(c2 * xs);
        const int it = i >> 4, r15 = i & 15;
        #pragma unroll
        for (int q = 0; q < 4; ++q) {
            half8 hh, hl;
            #pragma unroll
            for (int d = 0; d < 8; ++d) {
                float v = xp[q * 8 + d] * mf;
                _Float16 h = (_Float16)v;
                hh[d] = h;
                hl[d] = (_Float16)((v - (float)h) * 4096.0f);
            }
            xhl[it * 64 + q * 16 + r15].h = hh;
            xhl[it * 64 + q * 16 + r15].l = hl;
        }
    }
    if (i < m) {
        const float* yp = y + (size_t)i * DIM;
        double ys = 0.0;
        #pragma unroll
        for (int d = 0; d < DIM; ++d) { double v = (double)yp[d]; ys = fma(v, v, ys); }
        bf[i] = (float)(c2 * ys);
        const int it = i >> 4, r15 = i & 15;
        #pragma unroll
        for (int q = 0; q < 4; ++q) {
            half8 hh, hl;
            #pragma unroll
            for (int d = 0; d < 8; ++d) {
                float v = yp[q * 8 + d];
                _Float16 h = (_Float16)v;
                hh[d] = h;
                hl[d] = (_Float16)((v - (float)h) * 4096.0f);
            }
            yhl[it * 64 + q * 16 + r15].h = hh;
            yhl[it * 64 + q * 16 + r15].l = hl;
        }
    }
}

__global__ __launch_bounds__(BLK, 4) void rbf_main(
    const hl16* __restrict__ xhl, const hl16* __restrict__ yhl,
    const float* __restrict__ bf, double* __restrict__ acc, int chunk_j)
{
    const int lane = threadIdx.x & 63;
    const int wave = threadIdx.x >> 6;
    const int itbase = blockIdx.x * ITPB + wave * RI;
    const int c15 = lane & 15;

    half8 ah[RI], al[RI];
    #pragma unroll
    for (int r = 0; r < RI; ++r) {
        ah[r] = xhl[(itbase + r) * 64 + lane].h;
        al[r] = xhl[(itbase + r) * 64 + lane].l;
    }

    const int jt0 = (blockIdx.y * chunk_j) >> 4;
    const int njt = chunk_j >> 4;                 // 128 j-tiles per chunk

    const f32x4 zq = {0.0f, 0.0f, 0.0f, 0.0f};    // persistent zero C quad
    const float k12 = 0x1p-12f;

    double accd[RI][4];
    #pragma unroll
    for (int r = 0; r < RI; ++r)
        #pragma unroll
        for (int e = 0; e < 4; ++e) accd[r][e] = 0.0;

    // parity double-buffered B fragments
    half8 bh[2], bl[2];
    float bfv[2];
    bh[0] = yhl[(size_t)jt0 * 64 + lane].h;
    bl[0] = yhl[(size_t)jt0 * 64 + lane].l;
    bfv[0] = bf[jt0 * 16 + c15];

    for (int g = 0; g < njt / GTT; ++g) {
        // per-group uniform bases; per-tile offsets are compile-time consts
        const hl16*  __restrict__ ygrp = yhl + ((size_t)jt0 + (size_t)g * GTT) * 64;
        const float* __restrict__ bgrp = bf + (jt0 + g * GTT) * 16;

        float accf[RI][4];
        #pragma unroll
        for (int r = 0; r < RI; ++r)
            #pragma unroll
            for (int e = 0; e < 4; ++e) accf[r][e] = 0.0f;

        #pragma unroll
        for (int tt = 0; tt < GTT; ++tt) {
            const int cur = tt & 1, nxt = cur ^ 1;
            // prefetch tile tt+1 (at tt=GTT-1 of the last group this reads
            // one tile past the chunk — never consumed; layout keeps it in ws)
            bh[nxt] = ygrp[(tt + 1) * 64 + lane].h;
            bl[nxt] = ygrp[(tt + 1) * 64 + lane].l;
            bfv[nxt] = bgrp[(tt + 1) * 16 + c15];

            // bf*2^12 splat as the cl-chain C-init (shared across r)
            const float bq1 = bfv[cur] * 4096.0f;
            const f32x4 bq = {bq1, bq1, bq1, bq1};

            #pragma unroll
            for (int r = 0; r < RI; ++r) {
                f32x4 cm = __builtin_amdgcn_mfma_f32_16x16x32_f16(ah[r], bh[cur], zq, 0, 0, 0);
                f32x4 cl = __builtin_amdgcn_mfma_f32_16x16x32_f16(al[r], bh[cur], bq, 0, 0, 0);
                cl = __builtin_amdgcn_mfma_f32_16x16x32_f16(ah[r], bl[cur], cl, 0, 0, 0);
                #pragma unroll
                for (int e = 0; e < 4; ++e) {
                    float f = __builtin_fmaf(cl[e], k12, cm[e]);
                    accf[r][e] += __builtin_amdgcn_exp2f(f);
                }
            }
        }
        #pragma unroll
        for (int r = 0; r < RI; ++r)
            #pragma unroll
            for (int e = 0; e < 4; ++e) accd[r][e] += (double)accf[r][e];
    }

    // sum the 16 j-columns: fp64 butterfly across the 16-lane col groups
    #pragma unroll
    for (int r = 0; r < RI; ++r) {
        #pragma unroll
        for (int e = 0; e < 4; ++e) {
            double v = accd[r][e];
            v += __shfl_xor(v, 1, 64);
            v += __shfl_xor(v, 2, 64);
            v += __shfl_xor(v, 4, 64);
            v += __shfl_xor(v, 8, 64);
            if (c15 == 0) {
                int row = (itbase + r) * 16 + (lane >> 4) * 4 + e;
                atomicAdd(&acc[row], v);   // fp64, JSPLIT writers per row
            }
        }
    }
}

__global__ __launch_bounds__(BLK) void rbf_finish(
    const double* __restrict__ acc, const double* __restrict__ scale,
    float* __restrict__ out, int n)
{
    int i = blockIdx.x * BLK + threadIdx.x;
    if (i < n) out[i] = (float)(acc[i] * scale[i]);
}

extern "C" void kernel_launch(void* const* d_in, const int* in_sizes, int n_in,
                              void* d_out, int out_size, void* d_ws, size_t ws_size,
                              hipStream_t stream)
{
    const float* ls = (const float*)d_in[0];
    const float* x  = (const float*)d_in[1];
    const float* y  = (const float*)d_in[2];
    const int n = in_sizes[1] / DIM;   // 32768
    const int m = in_sizes[2] / DIM;   // 32768
    float* out = (float*)d_out;

    // ws layout (ORDER MATTERS — one-past-end prefetches must stay in ws):
    //   acc[n] f64 | scale[n] f64 | bf[m] f32 | yhl | xhl   (~8.6 MB)
    char* ws = (char*)d_ws;
    double* acc   = (double*)ws;
    double* scale = acc + n;
    float*  bf    = (float*)(scale + n);
    hl16*   yhl   = (hl16*)(bf + m);
    hl16*   xhl   = yhl + (size_t)(m / 16) * 64;

    const int nm = (n > m) ? n : m;
    rbf_prep<<<(nm + BLK - 1) / BLK, BLK, 0, stream>>>(
        ls, x, y, n, m, acc, scale, bf, xhl, yhl);

    const int chunk = m / JSPLIT;                 // 2048
    dim3 grid(n / (16 * ITPB), JSPLIT);           // 256 x 16
    rbf_main<<<grid, BLK, 0, stream>>>(xhl, yhl, bf, acc, chunk);

    rbf_finish<<<(n + BLK - 1) / BLK, BLK, 0, stream>>>(acc, scale, out, n);
}

// Round 10
// 294.208 us; speedup vs baseline: 7.5846x; 1.0344x over previous
//
#include <hip/hip_runtime.h>
#include <math.h>

#define DIM 32
#define BLK 256
#define JSPLIT 16   // j-chunks -> grid.y ; 16 fp64-atomic writers per out row
#define RI   2      // i-tiles per wave (32 rows) -> 512 pairs per wave-jtile
#define ITPB (4*RI) // i-tiles per block (8 tiles = 128 rows)
#define GTT  32     // j-tiles between fp32->fp64 flushes (512 j)

typedef _Float16 half8 __attribute__((ext_vector_type(8)));
typedef float    f32x4 __attribute__((ext_vector_type(4)));

struct hl16 { half8 h; half8 l; };   // 32 B fragment record (hi + lo plane)

// out[i] = 2^(c2*||x_i||^2) * sum_j 2^(bf_j + <mf*x_i, y_j>)
//   c2 = -ls*log2(e) (fp64, exact per-i factor in epilogue)
//   f16 hi/lo split (lo plane *2^12 to stay f16-normal):
//     cm = Ah*Bh ; cl = Ah*Bl + (Al*Bh + bf*2^12) ; f = fma(cl, 2^-12, cm)
//   exp2 = v_exp_f32; fp32 partials -> fp64 every GTT tiles; fp64 atomics.
// R9: __launch_bounds__(256,3) — 170-reg budget so the allocator keeps
//   MFMA accumulators in arch VGPRs (R3-R8 ran at 128-reg budget, VGPR=44
//   + AGPR-split => v_accvgpr round-trips in the hot loop). GTT 16->32
//   halves fp64-flush amortization. Structure otherwise identical to R8.

__global__ __launch_bounds__(BLK) void rbf_prep(
    const float* __restrict__ lsp, const float* __restrict__ x,
    const float* __restrict__ y, int n, int m,
    double* __restrict__ acc, double* __restrict__ scale,
    float* __restrict__ bf, hl16* __restrict__ xhl, hl16* __restrict__ yhl)
{
    int i = blockIdx.x * BLK + threadIdx.x;
    const double c2 = -(double)lsp[0] * 1.4426950408889634074; // -ls*log2(e)
    const float mf = (float)(-2.0 * c2);
    if (i < n) {
        const float* xp = x + (size_t)i * DIM;
        double xs = 0.0;
        #pragma unroll
        for (int d = 0; d < DIM; ++d) { double v = (double)xp[d]; xs = fma(v, v, xs); }
        acc[i] = 0.0;
        scale[i] = exp2(c2 * xs);
        const int it = i >> 4, r15 = i & 15;
        #pragma unroll
        for (int q = 0; q < 4; ++q) {
            half8 hh, hl;
            #pragma unroll
            for (int d = 0; d < 8; ++d) {
                float v = xp[q * 8 + d] * mf;
                _Float16 h = (_Float16)v;
                hh[d] = h;
                hl[d] = (_Float16)((v - (float)h) * 4096.0f);
            }
            xhl[it * 64 + q * 16 + r15].h = hh;
            xhl[it * 64 + q * 16 + r15].l = hl;
        }
    }
    if (i < m) {
        const float* yp = y + (size_t)i * DIM;
        double ys = 0.0;
        #pragma unroll
        for (int d = 0; d < DIM; ++d) { double v = (double)yp[d]; ys = fma(v, v, ys); }
        bf[i] = (float)(c2 * ys);
        const int it = i >> 4, r15 = i & 15;
        #pragma unroll
        for (int q = 0; q < 4; ++q) {
            half8 hh, hl;
            #pragma unroll
            for (int d = 0; d < 8; ++d) {
                float v = yp[q * 8 + d];
                _Float16 h = (_Float16)v;
                hh[d] = h;
                hl[d] = (_Float16)((v - (float)h) * 4096.0f);
            }
            yhl[it * 64 + q * 16 + r15].h = hh;
            yhl[it * 64 + q * 16 + r15].l = hl;
        }
    }
}

__global__ __launch_bounds__(BLK, 3) void rbf_main(
    const hl16* __restrict__ xhl, const hl16* __restrict__ yhl,
    const float* __restrict__ bf, double* __restrict__ acc, int chunk_j)
{
    const int lane = threadIdx.x & 63;
    const int wave = threadIdx.x >> 6;
    const int itbase = blockIdx.x * ITPB + wave * RI;
    const int c15 = lane & 15;

    half8 ah[RI], al[RI];
    #pragma unroll
    for (int r = 0; r < RI; ++r) {
        ah[r] = xhl[(itbase + r) * 64 + lane].h;
        al[r] = xhl[(itbase + r) * 64 + lane].l;
    }

    const int jt0 = (blockIdx.y * chunk_j) >> 4;
    const int njt = chunk_j >> 4;                 // 128 j-tiles per chunk

    const f32x4 zq = {0.0f, 0.0f, 0.0f, 0.0f};    // persistent zero C quad
    const float k12 = 0x1p-12f;

    double accd[RI][4];
    #pragma unroll
    for (int r = 0; r < RI; ++r)
        #pragma unroll
        for (int e = 0; e < 4; ++e) accd[r][e] = 0.0;

    // parity double-buffered B fragments
    half8 bh[2], bl[2];
    float bfv[2];
    bh[0] = yhl[(size_t)jt0 * 64 + lane].h;
    bl[0] = yhl[(size_t)jt0 * 64 + lane].l;
    bfv[0] = bf[jt0 * 16 + c15];

    for (int g = 0; g < njt / GTT; ++g) {
        // per-group uniform bases; per-tile offsets are compile-time consts
        const hl16*  __restrict__ ygrp = yhl + ((size_t)jt0 + (size_t)g * GTT) * 64;
        const float* __restrict__ bgrp = bf + (jt0 + g * GTT) * 16;

        float accf[RI][4];
        #pragma unroll
        for (int r = 0; r < RI; ++r)
            #pragma unroll
            for (int e = 0; e < 4; ++e) accf[r][e] = 0.0f;

        #pragma unroll
        for (int tt = 0; tt < GTT; ++tt) {
            const int cur = tt & 1, nxt = cur ^ 1;
            // prefetch tile tt+1 (at the last tile of the last group this
            // reads one tile past the chunk — never consumed; ws layout
            // keeps the stray load inside d_ws)
            bh[nxt] = ygrp[(tt + 1) * 64 + lane].h;
            bl[nxt] = ygrp[(tt + 1) * 64 + lane].l;
            bfv[nxt] = bgrp[(tt + 1) * 16 + c15];

            // bf*2^12 splat as the cl-chain C-init (shared across r)
            const float bq1 = bfv[cur] * 4096.0f;
            const f32x4 bq = {bq1, bq1, bq1, bq1};

            #pragma unroll
            for (int r = 0; r < RI; ++r) {
                f32x4 cm = __builtin_amdgcn_mfma_f32_16x16x32_f16(ah[r], bh[cur], zq, 0, 0, 0);
                f32x4 cl = __builtin_amdgcn_mfma_f32_16x16x32_f16(al[r], bh[cur], bq, 0, 0, 0);
                cl = __builtin_amdgcn_mfma_f32_16x16x32_f16(ah[r], bl[cur], cl, 0, 0, 0);
                #pragma unroll
                for (int e = 0; e < 4; ++e) {
                    float f = __builtin_fmaf(cl[e], k12, cm[e]);
                    accf[r][e] += __builtin_amdgcn_exp2f(f);
                }
            }
        }
        #pragma unroll
        for (int r = 0; r < RI; ++r)
            #pragma unroll
            for (int e = 0; e < 4; ++e) accd[r][e] += (double)accf[r][e];
    }

    // sum the 16 j-columns: fp64 butterfly across the 16-lane col groups
    #pragma unroll
    for (int r = 0; r < RI; ++r) {
        #pragma unroll
        for (int e = 0; e < 4; ++e) {
            double v = accd[r][e];
            v += __shfl_xor(v, 1, 64);
            v += __shfl_xor(v, 2, 64);
            v += __shfl_xor(v, 4, 64);
            v += __shfl_xor(v, 8, 64);
            if (c15 == 0) {
                int row = (itbase + r) * 16 + (lane >> 4) * 4 + e;
                atomicAdd(&acc[row], v);   // fp64, JSPLIT writers per row
            }
        }
    }
}

__global__ __launch_bounds__(BLK) void rbf_finish(
    const double* __restrict__ acc, const double* __restrict__ scale,
    float* __restrict__ out, int n)
{
    int i = blockIdx.x * BLK + threadIdx.x;
    if (i < n) out[i] = (float)(acc[i] * scale[i]);
}

extern "C" void kernel_launch(void* const* d_in, const int* in_sizes, int n_in,
                              void* d_out, int out_size, void* d_ws, size_t ws_size,
                              hipStream_t stream)
{
    const float* ls = (const float*)d_in[0];
    const float* x  = (const float*)d_in[1];
    const float* y  = (const float*)d_in[2];
    const int n = in_sizes[1] / DIM;   // 32768
    const int m = in_sizes[2] / DIM;   // 32768
    float* out = (float*)d_out;

    // ws layout (ORDER MATTERS — one-past-end prefetches must stay in ws):
    //   acc[n] f64 | scale[n] f64 | bf[m] f32 | yhl | xhl   (~8.6 MB)
    char* ws = (char*)d_ws;
    double* acc   = (double*)ws;
    double* scale = acc + n;
    float*  bf    = (float*)(scale + n);
    hl16*   yhl   = (hl16*)(bf + m);
    hl16*   xhl   = yhl + (size_t)(m / 16) * 64;

    const int nm = (n > m) ? n : m;
    rbf_prep<<<(nm + BLK - 1) / BLK, BLK, 0, stream>>>(
        ls, x, y, n, m, acc, scale, bf, xhl, yhl);

    const int chunk = m / JSPLIT;                 // 2048
    dim3 grid(n / (16 * ITPB), JSPLIT);           // 256 x 16
    rbf_main<<<grid, BLK, 0, stream>>>(xhl, yhl, bf, acc, chunk);

    rbf_finish<<<(n + BLK - 1) / BLK, BLK, 0, stream>>>(acc, scale, out, n);
}